// Round 6
// baseline (1511.773 us; speedup 1.0000x reference)
//
#include <hip/hip_runtime.h>

#define NN 100000        // nodes
#define NE 1600000       // edges
#define NRL 3            // relations
#define NG 1024          // graphs
#define NBUCK 3125       // NN/32 buckets of 32 nodes
#define ASTRIDE 768      // arena slots per bucket (mean 512, sigma~23 -> +11 sigma)

// ---------------- embed + lin0 + relu ----------------
__global__ void k_embed(const int* __restrict__ x_idx,
                        const float* __restrict__ semb, const float* __restrict__ cemb,
                        const float* __restrict__ w, const float* __restrict__ b,
                        float* __restrict__ xout) {
    __shared__ float s_w[16 * 64];
    __shared__ float s_se[64], s_ce[64], s_b[64];
    int t = threadIdx.x;
    for (int i = t; i < 16 * 64; i += 256) s_w[i] = w[i];
    if (t < 64) { s_se[t] = semb[t]; s_ce[t] = cemb[t]; s_b[t] = b[t]; }
    __syncthreads();
    int gid = blockIdx.x * 256 + t;           // grid exactly NN*64/256
    int v = gid >> 6, h = gid & 63;
    int si = x_idx[2 * v], ci = x_idx[2 * v + 1];
    float acc = s_b[h];
#pragma unroll
    for (int d = 0; d < 8; ++d) acc += s_se[si * 8 + d] * s_w[d * 64 + h];
#pragma unroll
    for (int d = 0; d < 8; ++d) acc += s_ce[ci * 8 + d] * s_w[(8 + d) * 64 + h];
    xout[gid] = fmaxf(acc, 0.f);
}

// ---------------- bucket build: append packed edge records per 32-node bucket ----------------
// rec = src (17b) | rel<<17 (2b) | (dst&31)<<19 (5b)
__global__ void k_bucket(const int* __restrict__ ei, const int* __restrict__ et,
                         int* __restrict__ bcnt, unsigned int* __restrict__ arena) {
    int e = blockIdx.x * 256 + threadIdx.x;
    if (e >= NE) return;
    int src = ei[e];
    int dst = ei[NE + e];
    int rel = et[e];
    int b = dst >> 5;
    unsigned int rec = (unsigned int)src | ((unsigned int)rel << 17) |
                       ((unsigned int)(dst & 31) << 19);
    int p = atomicAdd(&bcnt[b], 1);
    if (p < ASTRIDE) arena[(size_t)b * ASTRIDE + p] = rec;
}

// ---------------- bucketed mean aggregation: block per bucket, edge-parallel ----------------
// LDS acc[32][3][64] f32; edges processed 4-wide per wave with LDS atomic adds.
// Writes K[v][0:64)=mean_r0, [64:128)=mean_r1, [128:192)=mean_r2, [192:256)=x[v]
__global__ __launch_bounds__(256) void k_agg_bucket(
        const float* __restrict__ xin, const int* __restrict__ bcnt,
        const unsigned int* __restrict__ arena, float* __restrict__ K) {
    __shared__ float s_acc[32][3][64];
    __shared__ int s_cnt[32][3];
    int t = threadIdx.x;
    int wave = t >> 6, lane = t & 63;
    int b = blockIdx.x;

    for (int i = t; i < 32 * 3 * 64; i += 256) ((float*)s_acc)[i] = 0.f;
    if (t < 96) ((int*)s_cnt)[t] = 0;
    __syncthreads();

    int nb = bcnt[b]; if (nb > ASTRIDE) nb = ASTRIDE;
    const unsigned int* ab = arena + (size_t)b * ASTRIDE;

    int nfull = nb >> 2;                       // groups of 4 edges
    for (int g = wave; g < nfull; g += 4) {
        unsigned int r0 = ab[g * 4 + 0];
        unsigned int r1 = ab[g * 4 + 1];
        unsigned int r2 = ab[g * 4 + 2];
        unsigned int r3 = ab[g * 4 + 3];
        float x0 = xin[(size_t)(r0 & 0x1FFFF) * 64 + lane];
        float x1 = xin[(size_t)(r1 & 0x1FFFF) * 64 + lane];
        float x2 = xin[(size_t)(r2 & 0x1FFFF) * 64 + lane];
        float x3 = xin[(size_t)(r3 & 0x1FFFF) * 64 + lane];
        atomicAdd(&s_acc[(r0 >> 19) & 31][(r0 >> 17) & 3][lane], x0);
        atomicAdd(&s_acc[(r1 >> 19) & 31][(r1 >> 17) & 3][lane], x1);
        atomicAdd(&s_acc[(r2 >> 19) & 31][(r2 >> 17) & 3][lane], x2);
        atomicAdd(&s_acc[(r3 >> 19) & 31][(r3 >> 17) & 3][lane], x3);
        if (lane == 0) {
            atomicAdd(&s_cnt[(r0 >> 19) & 31][(r0 >> 17) & 3], 1);
            atomicAdd(&s_cnt[(r1 >> 19) & 31][(r1 >> 17) & 3], 1);
            atomicAdd(&s_cnt[(r2 >> 19) & 31][(r2 >> 17) & 3], 1);
            atomicAdd(&s_cnt[(r3 >> 19) & 31][(r3 >> 17) & 3], 1);
        }
    }
    if (wave == 0) {                           // tail 0..3 edges
        for (int e = nfull * 4; e < nb; ++e) {
            unsigned int r = ab[e];
            float x = xin[(size_t)(r & 0x1FFFF) * 64 + lane];
            atomicAdd(&s_acc[(r >> 19) & 31][(r >> 17) & 3][lane], x);
            if (lane == 0) atomicAdd(&s_cnt[(r >> 19) & 31][(r >> 17) & 3], 1);
        }
    }
    __syncthreads();

    // write-out: wave w -> nodes [b*32 + w*8, +8)
#pragma unroll
    for (int n = 0; n < 8; ++n) {
        int dlo = wave * 8 + n;
        int v = b * 32 + dlo;
        float* Kv = K + (size_t)v * 256;
#pragma unroll
        for (int r = 0; r < 3; ++r) {
            float inv = 1.f / fmaxf((float)s_cnt[dlo][r], 1.f);
            Kv[r * 64 + lane] = s_acc[dlo][r][lane] * inv;
        }
        Kv[192 + lane] = xin[(size_t)v * 64 + lane];
    }
}

// ---------------- dense transform: xout = relu(K @ [Wr0;Wr1;Wr2;Wroot] + b) ----------------
// 512 threads (8 waves). Wave owns 8 consecutive nodes = 8KB K slab.
// K pointer readfirstlane'd -> uniform -> s_load (SMEM pipe); FMA takes the K
// scalar as its SGPR operand. Inner loop: 4 LDS reads + 32 pure FMAs.
__global__ __launch_bounds__(512, 4) void k_transform(
        const float* __restrict__ K, const float* __restrict__ wrel,
        const float* __restrict__ wroot, const float* __restrict__ b,
        float* __restrict__ xout) {
    __shared__ float s_w[256 * 64];   // rows 0..191 = wrel, rows 192..255 = wroot
    __shared__ float s_b[64];
    int t = threadIdx.x;
    for (int i = t; i < 192 * 64; i += 512) s_w[i] = wrel[i];
    for (int i = t; i < 64 * 64; i += 512) s_w[192 * 64 + i] = wroot[i];
    if (t < 64) s_b[t] = b[t];
    __syncthreads();

    int wave = t >> 6, lane = t & 63;
    int v0 = blockIdx.x * 64 + wave * 8;   // 8 waves * 8 nodes = 64 nodes/block
    if (v0 >= NN) return;                   // NN % 8 == 0: active waves fully valid

    int v0u = __builtin_amdgcn_readfirstlane(v0);
    const float* Kb = K + (size_t)v0u * 256;   // uniform base -> scalar loads

    float acc[8];
    float bb = s_b[lane];
#pragma unroll
    for (int n = 0; n < 8; ++n) acc[n] = bb;

#pragma unroll 2
    for (int d4 = 0; d4 < 64; ++d4) {
        float w0 = s_w[(d4 * 4 + 0) * 64 + lane];
        float w1 = s_w[(d4 * 4 + 1) * 64 + lane];
        float w2 = s_w[(d4 * 4 + 2) * 64 + lane];
        float w3 = s_w[(d4 * 4 + 3) * 64 + lane];
#pragma unroll
        for (int n = 0; n < 8; ++n) {
            float k0 = Kb[n * 256 + d4 * 4 + 0];   // s_load_dwordx4
            float k1 = Kb[n * 256 + d4 * 4 + 1];
            float k2 = Kb[n * 256 + d4 * 4 + 2];
            float k3 = Kb[n * 256 + d4 * 4 + 3];
            acc[n] += k0 * w0;
            acc[n] += k1 * w1;
            acc[n] += k2 * w2;
            acc[n] += k3 * w3;
        }
    }

#pragma unroll
    for (int n = 0; n < 8; ++n)
        xout[(size_t)(v0 + n) * 64 + lane] = fmaxf(acc[n], 0.f);
}

// ---------------- global mean pool: wave-segmented over sorted batch ----------------
#define POOL_CHUNK 32
__global__ void k_pool(const float* __restrict__ x, const int* __restrict__ batch,
                       float* __restrict__ psum, int* __restrict__ pcnt) {
    int gwid = (blockIdx.x * 256 + threadIdx.x) >> 6;
    int lane = threadIdx.x & 63;
    int v0 = gwid * POOL_CHUNK;
    if (v0 >= NN) return;
    int v1 = v0 + POOL_CHUNK; if (v1 > NN) v1 = NN;
    float acc = 0.f;
    int cnt = 0;
    int gcur = batch[v0];
    for (int v = v0; v < v1; ++v) {
        int g = batch[v];
        if (g != gcur) {
            atomicAdd(&psum[gcur * 64 + lane], acc);
            if (lane == 0) atomicAdd(&pcnt[gcur], cnt);
            acc = 0.f; cnt = 0; gcur = g;
        }
        acc += x[(size_t)v * 64 + lane];
        ++cnt;
    }
    atomicAdd(&psum[gcur * 64 + lane], acc);
    if (lane == 0) atomicAdd(&pcnt[gcur], cnt);
}

__global__ void k_cls(const float* __restrict__ psum, const int* __restrict__ pcnt,
                      const float* __restrict__ w, const float* __restrict__ b,
                      float* __restrict__ out) {
    int gid = blockIdx.x * 256 + threadIdx.x;
    if (gid >= NG * 10) return;
    int g = gid / 10, c = gid % 10;
    float inv = 1.f / fmaxf((float)pcnt[g], 1.f);
    float acc = 0.f;
#pragma unroll
    for (int d = 0; d < 64; ++d) acc += psum[g * 64 + d] * w[d * 10 + c];
    out[gid] = acc * inv + b[c];
}

extern "C" void kernel_launch(void* const* d_in, const int* in_sizes, int n_in,
                              void* d_out, int out_size, void* d_ws, size_t ws_size,
                              hipStream_t stream) {
    const int*   x_idx  = (const int*)d_in[0];
    const int*   ei     = (const int*)d_in[1];
    const int*   et     = (const int*)d_in[2];
    const int*   batch  = (const int*)d_in[3];
    const float* semb   = (const float*)d_in[4];
    const float* cemb   = (const float*)d_in[5];
    const float* lin0w  = (const float*)d_in[6];
    const float* lin0b  = (const float*)d_in[7];
    const float* r1wrel = (const float*)d_in[8];
    const float* r1wroot= (const float*)d_in[9];
    const float* r1b    = (const float*)d_in[10];
    const float* r2wrel = (const float*)d_in[11];
    const float* r2wroot= (const float*)d_in[12];
    const float* r2b    = (const float*)d_in[13];
    const float* clsw   = (const float*)d_in[14];
    const float* clsb   = (const float*)d_in[15];
    float* out = (float*)d_out;

    char* ws = (char*)d_ws;
    size_t o = 0;
    auto alloc = [&](size_t bytes) -> void* {
        void* p = ws + o;
        o += (bytes + 255) & ~(size_t)255;
        return p;
    };
    int*          bcnt  = (int*)         alloc((size_t)NBUCK * 4);
    unsigned int* arena = (unsigned int*)alloc((size_t)NBUCK * ASTRIDE * 4);
    float*        xA    = (float*)       alloc((size_t)NN * 64 * 4);
    float*        xB    = (float*)       alloc((size_t)NN * 64 * 4);
    float*        Kbuf  = (float*)       alloc((size_t)NN * 256 * 4);
    float*        psum  = (float*)       alloc((size_t)NG * 64 * 4);
    int*          pcnt  = (int*)         alloc((size_t)NG * 4);

    hipMemsetAsync(bcnt, 0, (size_t)NBUCK * 4, stream);
    hipMemsetAsync(psum, 0, (size_t)NG * 64 * 4, stream);
    hipMemsetAsync(pcnt, 0, (size_t)NG * 4, stream);

    // node features
    k_embed<<<NN * 64 / 256, 256, 0, stream>>>(x_idx, semb, cemb, lin0w, lin0b, xA);

    // bucket build (once, reused by both layers)
    k_bucket<<<NE / 256, 256, 0, stream>>>(ei, et, bcnt, arena);

    // layer 1
    k_agg_bucket<<<NBUCK, 256, 0, stream>>>(xA, bcnt, arena, Kbuf);
    k_transform<<<(NN + 63) / 64, 512, 0, stream>>>(Kbuf, r1wrel, r1wroot, r1b, xB);
    // layer 2
    k_agg_bucket<<<NBUCK, 256, 0, stream>>>(xB, bcnt, arena, Kbuf);
    k_transform<<<(NN + 63) / 64, 512, 0, stream>>>(Kbuf, r2wrel, r2wroot, r2b, xA);

    // pool + classify
    {
        int nwaves = (NN + POOL_CHUNK - 1) / POOL_CHUNK;        // 3125
        int nblk = (nwaves * 64 + 255) / 256;                   // 782
        k_pool<<<nblk, 256, 0, stream>>>(xA, batch, psum, pcnt);
    }
    k_cls<<<(NG * 10 + 255) / 256, 256, 0, stream>>>(psum, pcnt, clsw, clsb, out);
}

// Round 7
// 566.425 us; speedup vs baseline: 2.6690x; 2.6690x over previous
//
#include <hip/hip_runtime.h>

#define NN 100000        // nodes
#define NE 1600000       // edges
#define NRL 3            // relations
#define NG 1024          // graphs
#define NBUCK 3125       // NN/32 buckets of 32 nodes
#define ASTRIDE 768      // arena slots per bucket (mean 512, sigma~23 -> +11 sigma)
#define OSTRIDE 104      // u16 offsets per bucket (96 starts + total, padded)

// ---------------- embed + lin0 + relu ----------------
__global__ void k_embed(const int* __restrict__ x_idx,
                        const float* __restrict__ semb, const float* __restrict__ cemb,
                        const float* __restrict__ w, const float* __restrict__ b,
                        float* __restrict__ xout) {
    __shared__ float s_w[16 * 64];
    __shared__ float s_se[64], s_ce[64], s_b[64];
    int t = threadIdx.x;
    for (int i = t; i < 16 * 64; i += 256) s_w[i] = w[i];
    if (t < 64) { s_se[t] = semb[t]; s_ce[t] = cemb[t]; s_b[t] = b[t]; }
    __syncthreads();
    int gid = blockIdx.x * 256 + t;           // grid exactly NN*64/256
    int v = gid >> 6, h = gid & 63;
    int si = x_idx[2 * v], ci = x_idx[2 * v + 1];
    float acc = s_b[h];
#pragma unroll
    for (int d = 0; d < 8; ++d) acc += s_se[si * 8 + d] * s_w[d * 64 + h];
#pragma unroll
    for (int d = 0; d < 8; ++d) acc += s_ce[ci * 8 + d] * s_w[(8 + d) * 64 + h];
    xout[gid] = fmaxf(acc, 0.f);
}

// ---------------- bucket build: append packed edge records per 32-node bucket ----------------
// rec = src (17b) | rel<<17 (2b) | (dst&31)<<19 (5b)
__global__ void k_bucket(const int* __restrict__ ei, const int* __restrict__ et,
                         int* __restrict__ bcnt, unsigned int* __restrict__ arena) {
    int e = blockIdx.x * 256 + threadIdx.x;
    if (e >= NE) return;
    int src = ei[e];
    int dst = ei[NE + e];
    int rel = et[e];
    int b = dst >> 5;
    unsigned int rec = (unsigned int)src | ((unsigned int)rel << 17) |
                       ((unsigned int)(dst & 31) << 19);
    int p = atomicAdd(&bcnt[b], 1);
    if (p < ASTRIDE) arena[(size_t)b * ASTRIDE + p] = rec;
}

// ---------------- per-bucket LDS counting sort: arena -> sorted src + local offsets ----------------
// key = dstlo*3 + rel (96 keys). In-place sorted writeback (coalesced), off16 = 96 starts + total.
__global__ __launch_bounds__(256) void k_sortbucket(
        const int* __restrict__ bcnt, unsigned int* __restrict__ arena,
        unsigned short* __restrict__ off16) {
    __shared__ unsigned int s_rec[ASTRIDE];
    __shared__ unsigned int s_srt[ASTRIDE];
    __shared__ int s_hist[97], s_start[97], s_pos[96];
    int t = threadIdx.x;
    int b = blockIdx.x;
    int nb = bcnt[b]; if (nb > ASTRIDE) nb = ASTRIDE;

    if (t < 97) s_hist[t] = 0;
    __syncthreads();
    for (int i = t; i < nb; i += 256) {
        unsigned int r = arena[(size_t)b * ASTRIDE + i];
        s_rec[i] = r;
        int key = ((r >> 19) & 31) * 3 + ((r >> 17) & 3);
        atomicAdd(&s_hist[key], 1);
    }
    __syncthreads();
    if (t == 0) {
        int run = 0;
#pragma unroll 8
        for (int k = 0; k < 96; ++k) { s_start[k] = run; run += s_hist[k]; }
        s_start[96] = run;                 // == nb
    }
    __syncthreads();
    if (t < 96) s_pos[t] = s_start[t];
    __syncthreads();
    for (int i = t; i < nb; i += 256) {
        unsigned int r = s_rec[i];
        int key = ((r >> 19) & 31) * 3 + ((r >> 17) & 3);
        int p = atomicAdd(&s_pos[key], 1);
        s_srt[p] = r & 0x1FFFF;            // keep src only
    }
    __syncthreads();
    for (int i = t; i < nb; i += 256)       // coalesced sequential writeback
        arena[(size_t)b * ASTRIDE + i] = s_srt[i];
    if (t < 97) off16[(size_t)b * OSTRIDE + t] = (unsigned short)s_start[t];
}

// ---------------- per-(r,dst) mean aggregation: wave per node (R5 structure) ----------------
// Fused loop over the node's sorted edge range; relation by boundary compare.
// Writes K[v][0:64)=mean_r0, [64:128)=mean_r1, [128:192)=mean_r2, [192:256)=x[v]
__global__ void k_agg(const float* __restrict__ xin, const unsigned int* __restrict__ arena,
                      const unsigned short* __restrict__ off16, float* __restrict__ K) {
    int wid = (blockIdx.x * 256 + threadIdx.x) >> 6;
    int lane = threadIdx.x & 63;
    if (wid >= NN) return;
    int v = wid;
    int b = v >> 5, dlo = v & 31;
    const unsigned short* ofs = off16 + (size_t)b * OSTRIDE + dlo * 3;
    int s0 = __builtin_amdgcn_readfirstlane((int)ofs[0]);
    int s1 = __builtin_amdgcn_readfirstlane((int)ofs[1]);
    int s2 = __builtin_amdgcn_readfirstlane((int)ofs[2]);
    int s3 = __builtin_amdgcn_readfirstlane((int)ofs[3]);
    const unsigned int* base = arena + (size_t)b * ASTRIDE;

    float a0 = 0.f, a1 = 0.f, a2 = 0.f;
    int e = s0;
    for (; e + 8 <= s3; e += 8) {
#pragma unroll
        for (int k = 0; k < 8; ++k) {
            int ee = e + k;
            int idx = (int)base[ee];                  // uniform -> s_load
            float x = xin[(size_t)idx * 64 + lane];   // coalesced 256B gather
            a0 += (ee < s1) ? x : 0.f;
            a1 += (ee >= s1 && ee < s2) ? x : 0.f;
            a2 += (ee >= s2) ? x : 0.f;
        }
    }
    for (; e < s3; ++e) {
        int idx = (int)base[e];
        float x = xin[(size_t)idx * 64 + lane];
        a0 += (e < s1) ? x : 0.f;
        a1 += (e >= s1 && e < s2) ? x : 0.f;
        a2 += (e >= s2) ? x : 0.f;
    }

    float* Kv = K + (size_t)v * 256;
    Kv[lane]       = a0 / fmaxf((float)(s1 - s0), 1.f);
    Kv[64 + lane]  = a1 / fmaxf((float)(s2 - s1), 1.f);
    Kv[128 + lane] = a2 / fmaxf((float)(s3 - s2), 1.f);
    Kv[192 + lane] = xin[(size_t)v * 64 + lane];
}

// ---------------- dense transform: xout = relu(K @ [Wr0;Wr1;Wr2;Wroot] + b) ----------------
// 512 threads (8 waves). Wave owns 8 consecutive nodes = 8KB K slab.
// K pointer readfirstlane'd -> uniform -> s_load (SMEM pipe); FMA takes the K
// scalar as its SGPR operand. Inner loop: 4 LDS reads + 32 pure FMAs.
__global__ __launch_bounds__(512, 4) void k_transform(
        const float* __restrict__ K, const float* __restrict__ wrel,
        const float* __restrict__ wroot, const float* __restrict__ b,
        float* __restrict__ xout) {
    __shared__ float s_w[256 * 64];   // rows 0..191 = wrel, rows 192..255 = wroot
    __shared__ float s_b[64];
    int t = threadIdx.x;
    for (int i = t; i < 192 * 64; i += 512) s_w[i] = wrel[i];
    for (int i = t; i < 64 * 64; i += 512) s_w[192 * 64 + i] = wroot[i];
    if (t < 64) s_b[t] = b[t];
    __syncthreads();

    int wave = t >> 6, lane = t & 63;
    int v0 = blockIdx.x * 64 + wave * 8;   // 8 waves * 8 nodes = 64 nodes/block
    if (v0 >= NN) return;                   // NN % 8 == 0: active waves fully valid

    int v0u = __builtin_amdgcn_readfirstlane(v0);
    const float* Kb = K + (size_t)v0u * 256;   // uniform base -> scalar loads

    float acc[8];
    float bb = s_b[lane];
#pragma unroll
    for (int n = 0; n < 8; ++n) acc[n] = bb;

#pragma unroll 2
    for (int d4 = 0; d4 < 64; ++d4) {
        float w0 = s_w[(d4 * 4 + 0) * 64 + lane];
        float w1 = s_w[(d4 * 4 + 1) * 64 + lane];
        float w2 = s_w[(d4 * 4 + 2) * 64 + lane];
        float w3 = s_w[(d4 * 4 + 3) * 64 + lane];
#pragma unroll
        for (int n = 0; n < 8; ++n) {
            float k0 = Kb[n * 256 + d4 * 4 + 0];   // s_load_dwordx4
            float k1 = Kb[n * 256 + d4 * 4 + 1];
            float k2 = Kb[n * 256 + d4 * 4 + 2];
            float k3 = Kb[n * 256 + d4 * 4 + 3];
            acc[n] += k0 * w0;
            acc[n] += k1 * w1;
            acc[n] += k2 * w2;
            acc[n] += k3 * w3;
        }
    }

#pragma unroll
    for (int n = 0; n < 8; ++n)
        xout[(size_t)(v0 + n) * 64 + lane] = fmaxf(acc[n], 0.f);
}

// ---------------- global mean pool: wave-segmented over sorted batch ----------------
#define POOL_CHUNK 32
__global__ void k_pool(const float* __restrict__ x, const int* __restrict__ batch,
                       float* __restrict__ psum, int* __restrict__ pcnt) {
    int gwid = (blockIdx.x * 256 + threadIdx.x) >> 6;
    int lane = threadIdx.x & 63;
    int v0 = gwid * POOL_CHUNK;
    if (v0 >= NN) return;
    int v1 = v0 + POOL_CHUNK; if (v1 > NN) v1 = NN;
    float acc = 0.f;
    int cnt = 0;
    int gcur = batch[v0];
    for (int v = v0; v < v1; ++v) {
        int g = batch[v];
        if (g != gcur) {
            atomicAdd(&psum[gcur * 64 + lane], acc);
            if (lane == 0) atomicAdd(&pcnt[gcur], cnt);
            acc = 0.f; cnt = 0; gcur = g;
        }
        acc += x[(size_t)v * 64 + lane];
        ++cnt;
    }
    atomicAdd(&psum[gcur * 64 + lane], acc);
    if (lane == 0) atomicAdd(&pcnt[gcur], cnt);
}

__global__ void k_cls(const float* __restrict__ psum, const int* __restrict__ pcnt,
                      const float* __restrict__ w, const float* __restrict__ b,
                      float* __restrict__ out) {
    int gid = blockIdx.x * 256 + threadIdx.x;
    if (gid >= NG * 10) return;
    int g = gid / 10, c = gid % 10;
    float inv = 1.f / fmaxf((float)pcnt[g], 1.f);
    float acc = 0.f;
#pragma unroll
    for (int d = 0; d < 64; ++d) acc += psum[g * 64 + d] * w[d * 10 + c];
    out[gid] = acc * inv + b[c];
}

extern "C" void kernel_launch(void* const* d_in, const int* in_sizes, int n_in,
                              void* d_out, int out_size, void* d_ws, size_t ws_size,
                              hipStream_t stream) {
    const int*   x_idx  = (const int*)d_in[0];
    const int*   ei     = (const int*)d_in[1];
    const int*   et     = (const int*)d_in[2];
    const int*   batch  = (const int*)d_in[3];
    const float* semb   = (const float*)d_in[4];
    const float* cemb   = (const float*)d_in[5];
    const float* lin0w  = (const float*)d_in[6];
    const float* lin0b  = (const float*)d_in[7];
    const float* r1wrel = (const float*)d_in[8];
    const float* r1wroot= (const float*)d_in[9];
    const float* r1b    = (const float*)d_in[10];
    const float* r2wrel = (const float*)d_in[11];
    const float* r2wroot= (const float*)d_in[12];
    const float* r2b    = (const float*)d_in[13];
    const float* clsw   = (const float*)d_in[14];
    const float* clsb   = (const float*)d_in[15];
    float* out = (float*)d_out;

    char* ws = (char*)d_ws;
    size_t o = 0;
    auto alloc = [&](size_t bytes) -> void* {
        void* p = ws + o;
        o += (bytes + 255) & ~(size_t)255;
        return p;
    };
    int*            bcnt  = (int*)           alloc((size_t)NBUCK * 4);
    unsigned int*   arena = (unsigned int*)  alloc((size_t)NBUCK * ASTRIDE * 4);
    unsigned short* off16 = (unsigned short*)alloc((size_t)NBUCK * OSTRIDE * 2);
    float*          xA    = (float*)         alloc((size_t)NN * 64 * 4);
    float*          xB    = (float*)         alloc((size_t)NN * 64 * 4);
    float*          Kbuf  = (float*)         alloc((size_t)NN * 256 * 4);
    float*          psum  = (float*)         alloc((size_t)NG * 64 * 4);
    int*            pcnt  = (int*)           alloc((size_t)NG * 4);

    hipMemsetAsync(bcnt, 0, (size_t)NBUCK * 4, stream);
    hipMemsetAsync(psum, 0, (size_t)NG * 64 * 4, stream);
    hipMemsetAsync(pcnt, 0, (size_t)NG * 4, stream);

    // node features
    k_embed<<<NN * 64 / 256, 256, 0, stream>>>(x_idx, semb, cemb, lin0w, lin0b, xA);

    // bucket build + per-bucket counting sort (once, reused by both layers)
    k_bucket<<<NE / 256, 256, 0, stream>>>(ei, et, bcnt, arena);
    k_sortbucket<<<NBUCK, 256, 0, stream>>>(bcnt, arena, off16);

    // layer 1
    k_agg<<<NN / 4, 256, 0, stream>>>(xA, arena, off16, Kbuf);
    k_transform<<<(NN + 63) / 64, 512, 0, stream>>>(Kbuf, r1wrel, r1wroot, r1b, xB);
    // layer 2
    k_agg<<<NN / 4, 256, 0, stream>>>(xB, arena, off16, Kbuf);
    k_transform<<<(NN + 63) / 64, 512, 0, stream>>>(Kbuf, r2wrel, r2wroot, r2b, xA);

    // pool + classify
    {
        int nwaves = (NN + POOL_CHUNK - 1) / POOL_CHUNK;        // 3125
        int nblk = (nwaves * 64 + 255) / 256;                   // 782
        k_pool<<<nblk, 256, 0, stream>>>(xA, batch, psum, pcnt);
    }
    k_cls<<<(NG * 10 + 255) / 256, 256, 0, stream>>>(psum, pcnt, clsw, clsb, out);
}

// Round 8
// 505.138 us; speedup vs baseline: 2.9928x; 1.1213x over previous
//
#include <hip/hip_runtime.h>

#define NN 100000        // nodes
#define NE 1600000       // edges
#define NRL 3            // relations
#define NG 1024          // graphs
#define NBUCK 3125       // NN/32 buckets of 32 nodes
#define NXCD 8
#define PSTRIDE 128      // slots per (bucket, xcd): mean 64, sigma 8 -> +8 sigma
#define BSLOTS (NXCD * PSTRIDE)   // 1024 slots per bucket
#define OSTRIDE 104      // u16 offsets per bucket (96 starts + total, padded)

__device__ __forceinline__ int xcd_id() {
    unsigned int x;
    asm volatile("s_getreg_b32 %0, hwreg(HW_REG_XCC_ID)" : "=s"(x));
    return (int)(x & 7);
}

// ---------------- embed + lin0 + relu ----------------
__global__ void k_embed(const int* __restrict__ x_idx,
                        const float* __restrict__ semb, const float* __restrict__ cemb,
                        const float* __restrict__ w, const float* __restrict__ b,
                        float* __restrict__ xout) {
    __shared__ float s_w[16 * 64];
    __shared__ float s_se[64], s_ce[64], s_b[64];
    int t = threadIdx.x;
    for (int i = t; i < 16 * 64; i += 256) s_w[i] = w[i];
    if (t < 64) { s_se[t] = semb[t]; s_ce[t] = cemb[t]; s_b[t] = b[t]; }
    __syncthreads();
    int gid = blockIdx.x * 256 + t;           // grid exactly NN*64/256
    int v = gid >> 6, h = gid & 63;
    int si = x_idx[2 * v], ci = x_idx[2 * v + 1];
    float acc = s_b[h];
#pragma unroll
    for (int d = 0; d < 8; ++d) acc += s_se[si * 8 + d] * s_w[d * 64 + h];
#pragma unroll
    for (int d = 0; d < 8; ++d) acc += s_ce[ci * 8 + d] * s_w[(8 + d) * 64 + h];
    xout[gid] = fmaxf(acc, 0.f);
}

// ---------------- bucket build: XCD-private append of packed edge records ----------------
// rec = src (17b) | rel<<17 (2b) | (dst&31)<<19 (5b)
__global__ void k_bucket(const int* __restrict__ ei, const int* __restrict__ et,
                         int* __restrict__ bcnt, unsigned int* __restrict__ arena) {
    int e = blockIdx.x * 256 + threadIdx.x;
    if (e >= NE) return;
    int p = xcd_id();                          // wave-uniform physical XCD
    int src = ei[e];
    int dst = ei[NE + e];
    int rel = et[e];
    int b = dst >> 5;
    unsigned int rec = (unsigned int)src | ((unsigned int)rel << 17) |
                       ((unsigned int)(dst & 31) << 19);
    int cell = b * NXCD + p;
    int pos = atomicAdd(&bcnt[cell], 1);
    if (pos < PSTRIDE) arena[(size_t)cell * PSTRIDE + pos] = rec;
}

// ---------------- per-bucket LDS counting sort: 8 partitions -> sorted src + offsets ----------------
// key = dstlo*3 + rel (96 keys). Packed sorted writeback at bucket base (stride BSLOTS).
__global__ __launch_bounds__(256) void k_sortbucket(
        const int* __restrict__ bcnt, unsigned int* __restrict__ arena,
        unsigned short* __restrict__ off16) {
    __shared__ unsigned int s_rec[BSLOTS];
    __shared__ unsigned int s_srt[BSLOTS];
    __shared__ int s_hist[97], s_start[97], s_pos[96];
    int t = threadIdx.x;
    int b = blockIdx.x;

    if (t < 97) s_hist[t] = 0;
    __syncthreads();

    int tot = 0;
#pragma unroll
    for (int p = 0; p < NXCD; ++p) {
        int c = bcnt[b * NXCD + p]; if (c > PSTRIDE) c = PSTRIDE;
        const unsigned int* src = arena + ((size_t)(b * NXCD + p)) * PSTRIDE;
        for (int i = t; i < c; i += 256) {
            unsigned int r = src[i];
            s_rec[tot + i] = r;
            int key = ((r >> 19) & 31) * 3 + ((r >> 17) & 3);
            atomicAdd(&s_hist[key], 1);
        }
        tot += c;
    }
    __syncthreads();
    if (t == 0) {
        int run = 0;
#pragma unroll 8
        for (int k = 0; k < 96; ++k) { s_start[k] = run; run += s_hist[k]; }
        s_start[96] = run;                 // == tot
    }
    __syncthreads();
    if (t < 96) s_pos[t] = s_start[t];
    __syncthreads();
    for (int i = t; i < tot; i += 256) {
        unsigned int r = s_rec[i];
        int key = ((r >> 19) & 31) * 3 + ((r >> 17) & 3);
        int p = atomicAdd(&s_pos[key], 1);
        s_srt[p] = r & 0x1FFFF;            // keep src only
    }
    __syncthreads();
    for (int i = t; i < tot; i += 256)      // coalesced packed writeback at bucket base
        arena[(size_t)b * BSLOTS + i] = s_srt[i];
    if (t < 97) off16[(size_t)b * OSTRIDE + t] = (unsigned short)s_start[t];
}

// ---------------- per-(r,dst) mean aggregation: wave per node ----------------
// Fused loop over the node's sorted edge range; relation by boundary compare.
// Writes K[v][0:64)=mean_r0, [64:128)=mean_r1, [128:192)=mean_r2, [192:256)=x[v]
__global__ void k_agg(const float* __restrict__ xin, const unsigned int* __restrict__ arena,
                      const unsigned short* __restrict__ off16, float* __restrict__ K) {
    int wid = (blockIdx.x * 256 + threadIdx.x) >> 6;
    int lane = threadIdx.x & 63;
    if (wid >= NN) return;
    int v = wid;
    int b = v >> 5, dlo = v & 31;
    const unsigned short* ofs = off16 + (size_t)b * OSTRIDE + dlo * 3;
    int s0 = __builtin_amdgcn_readfirstlane((int)ofs[0]);
    int s1 = __builtin_amdgcn_readfirstlane((int)ofs[1]);
    int s2 = __builtin_amdgcn_readfirstlane((int)ofs[2]);
    int s3 = __builtin_amdgcn_readfirstlane((int)ofs[3]);
    const unsigned int* base = arena + (size_t)b * BSLOTS;

    float a0 = 0.f, a1 = 0.f, a2 = 0.f;
    int e = s0;
    for (; e + 8 <= s3; e += 8) {
#pragma unroll
        for (int k = 0; k < 8; ++k) {
            int ee = e + k;
            int idx = (int)base[ee];                  // uniform -> s_load
            float x = xin[(size_t)idx * 64 + lane];   // coalesced 256B gather
            a0 += (ee < s1) ? x : 0.f;
            a1 += (ee >= s1 && ee < s2) ? x : 0.f;
            a2 += (ee >= s2) ? x : 0.f;
        }
    }
    for (; e < s3; ++e) {
        int idx = (int)base[e];
        float x = xin[(size_t)idx * 64 + lane];
        a0 += (e < s1) ? x : 0.f;
        a1 += (e >= s1 && e < s2) ? x : 0.f;
        a2 += (e >= s2) ? x : 0.f;
    }

    float* Kv = K + (size_t)v * 256;
    Kv[lane]       = a0 / fmaxf((float)(s1 - s0), 1.f);
    Kv[64 + lane]  = a1 / fmaxf((float)(s2 - s1), 1.f);
    Kv[128 + lane] = a2 / fmaxf((float)(s3 - s2), 1.f);
    Kv[192 + lane] = xin[(size_t)v * 64 + lane];
}

// ---------------- dense transform: xout = relu(K @ [Wr0;Wr1;Wr2;Wroot] + b) ----------------
// 512 threads (8 waves). Wave owns 8 consecutive nodes = 8KB K slab.
// K pointer readfirstlane'd -> uniform -> s_load (SMEM pipe); FMA takes the K
// scalar as its SGPR operand. Inner loop: 4 LDS reads + 32 pure FMAs.
__global__ __launch_bounds__(512, 4) void k_transform(
        const float* __restrict__ K, const float* __restrict__ wrel,
        const float* __restrict__ wroot, const float* __restrict__ b,
        float* __restrict__ xout) {
    __shared__ float s_w[256 * 64];   // rows 0..191 = wrel, rows 192..255 = wroot
    __shared__ float s_b[64];
    int t = threadIdx.x;
    for (int i = t; i < 192 * 64; i += 512) s_w[i] = wrel[i];
    for (int i = t; i < 64 * 64; i += 512) s_w[192 * 64 + i] = wroot[i];
    if (t < 64) s_b[t] = b[t];
    __syncthreads();

    int wave = t >> 6, lane = t & 63;
    int v0 = blockIdx.x * 64 + wave * 8;   // 8 waves * 8 nodes = 64 nodes/block
    if (v0 >= NN) return;                   // NN % 8 == 0: active waves fully valid

    int v0u = __builtin_amdgcn_readfirstlane(v0);
    const float* Kb = K + (size_t)v0u * 256;   // uniform base -> scalar loads

    float acc[8];
    float bb = s_b[lane];
#pragma unroll
    for (int n = 0; n < 8; ++n) acc[n] = bb;

#pragma unroll 2
    for (int d4 = 0; d4 < 64; ++d4) {
        float w0 = s_w[(d4 * 4 + 0) * 64 + lane];
        float w1 = s_w[(d4 * 4 + 1) * 64 + lane];
        float w2 = s_w[(d4 * 4 + 2) * 64 + lane];
        float w3 = s_w[(d4 * 4 + 3) * 64 + lane];
#pragma unroll
        for (int n = 0; n < 8; ++n) {
            float k0 = Kb[n * 256 + d4 * 4 + 0];   // s_load_dwordx4
            float k1 = Kb[n * 256 + d4 * 4 + 1];
            float k2 = Kb[n * 256 + d4 * 4 + 2];
            float k3 = Kb[n * 256 + d4 * 4 + 3];
            acc[n] += k0 * w0;
            acc[n] += k1 * w1;
            acc[n] += k2 * w2;
            acc[n] += k3 * w3;
        }
    }

#pragma unroll
    for (int n = 0; n < 8; ++n)
        xout[(size_t)(v0 + n) * 64 + lane] = fmaxf(acc[n], 0.f);
}

// ---------------- global mean pool: wave-segmented over sorted batch ----------------
#define POOL_CHUNK 32
__global__ void k_pool(const float* __restrict__ x, const int* __restrict__ batch,
                       float* __restrict__ psum, int* __restrict__ pcnt) {
    int gwid = (blockIdx.x * 256 + threadIdx.x) >> 6;
    int lane = threadIdx.x & 63;
    int v0 = gwid * POOL_CHUNK;
    if (v0 >= NN) return;
    int v1 = v0 + POOL_CHUNK; if (v1 > NN) v1 = NN;
    float acc = 0.f;
    int cnt = 0;
    int gcur = batch[v0];
    for (int v = v0; v < v1; ++v) {
        int g = batch[v];
        if (g != gcur) {
            atomicAdd(&psum[gcur * 64 + lane], acc);
            if (lane == 0) atomicAdd(&pcnt[gcur], cnt);
            acc = 0.f; cnt = 0; gcur = g;
        }
        acc += x[(size_t)v * 64 + lane];
        ++cnt;
    }
    atomicAdd(&psum[gcur * 64 + lane], acc);
    if (lane == 0) atomicAdd(&pcnt[gcur], cnt);
}

__global__ void k_cls(const float* __restrict__ psum, const int* __restrict__ pcnt,
                      const float* __restrict__ w, const float* __restrict__ b,
                      float* __restrict__ out) {
    int gid = blockIdx.x * 256 + threadIdx.x;
    if (gid >= NG * 10) return;
    int g = gid / 10, c = gid % 10;
    float inv = 1.f / fmaxf((float)pcnt[g], 1.f);
    float acc = 0.f;
#pragma unroll
    for (int d = 0; d < 64; ++d) acc += psum[g * 64 + d] * w[d * 10 + c];
    out[gid] = acc * inv + b[c];
}

extern "C" void kernel_launch(void* const* d_in, const int* in_sizes, int n_in,
                              void* d_out, int out_size, void* d_ws, size_t ws_size,
                              hipStream_t stream) {
    const int*   x_idx  = (const int*)d_in[0];
    const int*   ei     = (const int*)d_in[1];
    const int*   et     = (const int*)d_in[2];
    const int*   batch  = (const int*)d_in[3];
    const float* semb   = (const float*)d_in[4];
    const float* cemb   = (const float*)d_in[5];
    const float* lin0w  = (const float*)d_in[6];
    const float* lin0b  = (const float*)d_in[7];
    const float* r1wrel = (const float*)d_in[8];
    const float* r1wroot= (const float*)d_in[9];
    const float* r1b    = (const float*)d_in[10];
    const float* r2wrel = (const float*)d_in[11];
    const float* r2wroot= (const float*)d_in[12];
    const float* r2b    = (const float*)d_in[13];
    const float* clsw   = (const float*)d_in[14];
    const float* clsb   = (const float*)d_in[15];
    float* out = (float*)d_out;

    char* ws = (char*)d_ws;
    size_t o = 0;
    auto alloc = [&](size_t bytes) -> void* {
        void* p = ws + o;
        o += (bytes + 255) & ~(size_t)255;
        return p;
    };
    int*            bcnt  = (int*)           alloc((size_t)NBUCK * NXCD * 4);
    unsigned int*   arena = (unsigned int*)  alloc((size_t)NBUCK * BSLOTS * 4);
    unsigned short* off16 = (unsigned short*)alloc((size_t)NBUCK * OSTRIDE * 2);
    float*          xA    = (float*)         alloc((size_t)NN * 64 * 4);
    float*          xB    = (float*)         alloc((size_t)NN * 64 * 4);
    float*          Kbuf  = (float*)         alloc((size_t)NN * 256 * 4);
    float*          psum  = (float*)         alloc((size_t)NG * 64 * 4);
    int*            pcnt  = (int*)           alloc((size_t)NG * 4);

    hipMemsetAsync(bcnt, 0, (size_t)NBUCK * NXCD * 4, stream);
    hipMemsetAsync(psum, 0, (size_t)NG * 64 * 4, stream);
    hipMemsetAsync(pcnt, 0, (size_t)NG * 4, stream);

    // node features
    k_embed<<<NN * 64 / 256, 256, 0, stream>>>(x_idx, semb, cemb, lin0w, lin0b, xA);

    // bucket build (XCD-private) + per-bucket counting sort (once, reused by both layers)
    k_bucket<<<NE / 256, 256, 0, stream>>>(ei, et, bcnt, arena);
    k_sortbucket<<<NBUCK, 256, 0, stream>>>(bcnt, arena, off16);

    // layer 1
    k_agg<<<NN / 4, 256, 0, stream>>>(xA, arena, off16, Kbuf);
    k_transform<<<(NN + 63) / 64, 512, 0, stream>>>(Kbuf, r1wrel, r1wroot, r1b, xB);
    // layer 2
    k_agg<<<NN / 4, 256, 0, stream>>>(xB, arena, off16, Kbuf);
    k_transform<<<(NN + 63) / 64, 512, 0, stream>>>(Kbuf, r2wrel, r2wroot, r2b, xA);

    // pool + classify
    {
        int nwaves = (NN + POOL_CHUNK - 1) / POOL_CHUNK;        // 3125
        int nblk = (nwaves * 64 + 255) / 256;                   // 782
        k_pool<<<nblk, 256, 0, stream>>>(xA, batch, psum, pcnt);
    }
    k_cls<<<(NG * 10 + 255) / 256, 256, 0, stream>>>(psum, pcnt, clsw, clsb, out);
}